// Round 1
// baseline (202.216 us; speedup 1.0000x reference)
//
#include <hip/hip_runtime.h>

// ---------------------------------------------------------------------------
// NearestSim: out[t] = -cos(q_t, items[argmax_j q_t . items_j])
// T=16384 queries, M=4096 items, C=512 channels, fp32 in/out.
//
// Strategy: fp16 MFMA fused GEMM-argmax (top-2 per query), exact fp32 rescue.
// ---------------------------------------------------------------------------

#define TQ 16384
#define MI 4096
#define CD 512
#define NSPLIT 4
#define BM 128
#define BN 128
#define BK 32
#define NT_PER (MI / (NSPLIT * BN))   // 8 item-tiles per block
#define KITER (CD / BK)               // 16 k-iterations

typedef _Float16 half8   __attribute__((ext_vector_type(8)));
typedef _Float16 half4_t __attribute__((ext_vector_type(4)));
typedef float    float4t __attribute__((ext_vector_type(4)));

// workspace layout (bytes)
#define QH_OFF   (0u)
#define QH_BYTES ((unsigned)TQ * CD * 2u)          // 16 MB  fp16 queries
#define IH_OFF   (QH_OFF + QH_BYTES)
#define IH_BYTES ((unsigned)MI * CD * 2u)          // 4 MB   fp16 items
#define PV_OFF   (IH_OFF + IH_BYTES)
#define PV_BYTES ((unsigned)NSPLIT * TQ * 8u)      // float2 top-2 values
#define PI_OFF   (PV_OFF + PV_BYTES)
#define PI_BYTES ((unsigned)NSPLIT * TQ * 8u)      // int2 top-2 indices
// total ~22 MB

__device__ __forceinline__ void lds_load16(const void* g, void* l) {
  __builtin_amdgcn_global_load_lds(
      (const __attribute__((address_space(1))) void*)g,
      (__attribute__((address_space(3))) void*)l, 16, 0, 0);
}

__device__ __forceinline__ void top2_update(float& t1v, int& t1i, float& t2v,
                                            int& t2i, float v, int idx) {
  bool g1 = (v > t1v);
  bool g2 = (v > t2v);
  float nt2v = g1 ? t1v : (g2 ? v : t2v);
  int   nt2i = g1 ? t1i : (g2 ? idx : t2i);
  t1v = g1 ? v : t1v;
  t1i = g1 ? idx : t1i;
  t2v = nt2v;
  t2i = nt2i;
}

// merge sorted pair (b1,b2) into sorted pair (a1,a2); ties prefer lower index
__device__ __forceinline__ void top2_merge(float& a1v, int& a1i, float& a2v,
                                           int& a2i, float b1v, int b1i,
                                           float b2v, int b2i) {
  bool af = (a1v > b1v) || (a1v == b1v && a1i <= b1i);
  float w1v = af ? a1v : b1v; int w1i = af ? a1i : b1i;
  float l1v = af ? b1v : a1v; int l1i = af ? b1i : a1i;
  float c2v = af ? a2v : b2v; int c2i = af ? a2i : b2i;
  bool lb = (l1v > c2v) || (l1v == c2v && l1i <= c2i);
  a1v = w1v; a1i = w1i;
  a2v = lb ? l1v : c2v;
  a2i = lb ? l1i : c2i;
}

// ---------------- kernel 1: fp32 -> fp16 conversion into workspace ----------
__global__ __launch_bounds__(256) void convert_kernel(
    const float* __restrict__ q, const float* __restrict__ it,
    char* __restrict__ ws) {
  int idx = blockIdx.x * 256 + threadIdx.x;
  const int QV = TQ * CD / 4;  // 2097152 float4s
  const int IV = MI * CD / 4;  //  524288 float4s
  half4_t* Qh = (half4_t*)(ws + QH_OFF);
  half4_t* Ih = (half4_t*)(ws + IH_OFF);
  if (idx < QV) {
    float4 v = ((const float4*)q)[idx];
    half4_t h = {(_Float16)v.x, (_Float16)v.y, (_Float16)v.z, (_Float16)v.w};
    Qh[idx] = h;
  }
  if (idx < IV) {
    float4 v = ((const float4*)it)[idx];
    half4_t h = {(_Float16)v.x, (_Float16)v.y, (_Float16)v.z, (_Float16)v.w};
    Ih[idx] = h;
  }
}

// ---------------- kernel 2: fused fp16 GEMM + per-query top-2 ---------------
// grid (TQ/BM, NSPLIT), block 256 (4 waves). Wave tile: 32 queries x 128 items
// (2x8 grid of 16x16x32 MFMAs) so each query row lives entirely in one wave.
__global__ __launch_bounds__(256, 2) void score_kernel(char* __restrict__ ws) {
  __shared__ __align__(16) char sA[BM * BK * 2];  // 8 KB
  __shared__ __align__(16) char sB[BN * BK * 2];  // 8 KB

  const int tid   = threadIdx.x;
  const int lane  = tid & 63;
  const int wave  = tid >> 6;
  const int quad  = lane >> 4;
  const int l15   = lane & 15;
  const int qtile = blockIdx.x;
  const int split = blockIdx.y;

  const char* Qh = ws + QH_OFF;
  const char* Ih = ws + IH_OFF;

  // staging: 8 KB tile = 256 threads x 2 x 16B. flat LDS offset (wave-contig,
  // lane*16 within wave -> satisfies global_load_lds layout constraint)
  const int srow = tid >> 2;           // 0..63
  const int scol = (tid & 3) * 16;     // byte within 64B row
  const int flat0 = tid * 16;          // LDS byte offset, loads 0
  const int flat1 = flat0 + 4096;      // loads 1 (rows 64..127)
  const char* gA0 = Qh + (size_t)(qtile * BM + srow) * 1024 + scol;
  const char* gA1 = gA0 + 64 * 1024;

  // fragment LDS byte offsets (constant across k since tile is one k-slice)
  int aOff[2], bOff[8];
#pragma unroll
  for (int mi = 0; mi < 2; ++mi)
    aOff[mi] = (wave * 32 + mi * 16 + l15) * 64 + quad * 16;
#pragma unroll
  for (int ni = 0; ni < 8; ++ni)
    bOff[ni] = (ni * 16 + l15) * 64 + quad * 16;

  // per-lane running top-2 for the 8 query rows this lane touches
  float t1v[8], t2v[8];
  int t1i[8], t2i[8];
#pragma unroll
  for (int s = 0; s < 8; ++s) {
    t1v[s] = -1e30f; t2v[s] = -1e30f; t1i[s] = 0; t2i[s] = 0;
  }

  for (int nt = 0; nt < NT_PER; ++nt) {
    const int nb = split * (MI / NSPLIT) + nt * BN;
    const char* gB0 = Ih + (size_t)(nb + srow) * 1024 + scol;
    const char* gB1 = gB0 + 64 * 1024;

    float4t acc[2][8];
#pragma unroll
    for (int mi = 0; mi < 2; ++mi)
#pragma unroll
      for (int ni = 0; ni < 8; ++ni) acc[mi][ni] = (float4t){0.f, 0.f, 0.f, 0.f};

    for (int kk = 0; kk < KITER; ++kk) {
      const int kb = kk * 64;  // 32 fp16 = 64 bytes per k-slice
      __syncthreads();         // previous tile fully consumed
      lds_load16(gA0 + kb, sA + flat0);
      lds_load16(gA1 + kb, sA + flat1);
      lds_load16(gB0 + kb, sB + flat0);
      lds_load16(gB1 + kb, sB + flat1);
      __syncthreads();         // drains vmcnt before barrier (compiler-enforced)

      half8 a[2], b[8];
#pragma unroll
      for (int mi = 0; mi < 2; ++mi) a[mi] = *(const half8*)(sA + aOff[mi]);
#pragma unroll
      for (int ni = 0; ni < 8; ++ni) b[ni] = *(const half8*)(sB + bOff[ni]);
#pragma unroll
      for (int mi = 0; mi < 2; ++mi)
#pragma unroll
        for (int ni = 0; ni < 8; ++ni)
          acc[mi][ni] = __builtin_amdgcn_mfma_f32_16x16x32_f16(
              a[mi], b[ni], acc[mi][ni], 0, 0, 0);
    }

    // top-2 epilogue: C/D layout row = quad*4+r (query), col = lane&15 (item)
#pragma unroll
    for (int mi = 0; mi < 2; ++mi) {
#pragma unroll
      for (int ni = 0; ni < 8; ++ni) {
        const int idx = nb + ni * 16 + l15;
#pragma unroll
        for (int r = 0; r < 4; ++r) {
          const int s = mi * 4 + r;
          top2_update(t1v[s], t1i[s], t2v[s], t2i[s], acc[mi][ni][r], idx);
        }
      }
    }
  }

  // cross-lane merge within each 16-lane group (same quad covers same rows)
#pragma unroll
  for (int s = 0; s < 8; ++s) {
#pragma unroll
    for (int m = 1; m < 16; m <<= 1) {
      float o1v = __shfl_xor(t1v[s], m, 16);
      int   o1i = __shfl_xor(t1i[s], m, 16);
      float o2v = __shfl_xor(t2v[s], m, 16);
      int   o2i = __shfl_xor(t2i[s], m, 16);
      top2_merge(t1v[s], t1i[s], t2v[s], t2i[s], o1v, o1i, o2v, o2i);
    }
  }

  // lane l15==s writes row (mi = s>>2, r = s&3) of its quad
  float2* pv = (float2*)(ws + PV_OFF);
  int2*   pi = (int2*)(ws + PI_OFF);
#pragma unroll
  for (int s = 0; s < 8; ++s) {
    if (l15 == s) {
      const int mi = s >> 2, r = s & 3;
      const int qrow = qtile * BM + wave * 32 + mi * 16 + quad * 4 + r;
      pv[split * TQ + qrow] = make_float2(t1v[s], t2v[s]);
      pi[split * TQ + qrow] = make_int2(t1i[s], t2i[s]);
    }
  }
}

// ---------------- kernel 3: combine splits + exact fp32 rescue --------------
// one wave per query; candidates = global fp16 top-2; re-score both in fp32.
__global__ __launch_bounds__(256) void rescue_kernel(
    const float* __restrict__ q, const float* __restrict__ items,
    const char* __restrict__ ws, float* __restrict__ out) {
  const int wave = threadIdx.x >> 6;
  const int lane = threadIdx.x & 63;
  const int qrow = blockIdx.x * 4 + wave;

  const float2* pv = (const float2*)(ws + PV_OFF);
  const int2*   pi = (const int2*)(ws + PI_OFF);

  float c1v = -1e30f, c2v = -1e30f;
  int c1i = 0x7fffffff, c2i = 0x7fffffff;
#pragma unroll
  for (int s = 0; s < NSPLIT; ++s) {
    float2 v = pv[s * TQ + qrow];
    int2 id = pi[s * TQ + qrow];
    top2_merge(c1v, c1i, c2v, c2i, v.x, id.x, v.y, id.y);
  }

  const float4* qp = (const float4*)(q + (size_t)qrow * CD);
  const float4* p1 = (const float4*)(items + (size_t)c1i * CD);
  const float4* p2 = (const float4*)(items + (size_t)c2i * CD);
  float4 qa = qp[lane * 2], qb = qp[lane * 2 + 1];
  float4 xa = p1[lane * 2], xb = p1[lane * 2 + 1];
  float4 ya = p2[lane * 2], yb = p2[lane * 2 + 1];

  float d1 = qa.x * xa.x + qa.y * xa.y + qa.z * xa.z + qa.w * xa.w +
             qb.x * xb.x + qb.y * xb.y + qb.z * xb.z + qb.w * xb.w;
  float d2 = qa.x * ya.x + qa.y * ya.y + qa.z * ya.z + qa.w * ya.w +
             qb.x * yb.x + qb.y * yb.y + qb.z * yb.z + qb.w * yb.w;
  float qq = qa.x * qa.x + qa.y * qa.y + qa.z * qa.z + qa.w * qa.w +
             qb.x * qb.x + qb.y * qb.y + qb.z * qb.z + qb.w * qb.w;
  float i1 = xa.x * xa.x + xa.y * xa.y + xa.z * xa.z + xa.w * xa.w +
             xb.x * xb.x + xb.y * xb.y + xb.z * xb.z + xb.w * xb.w;
  float i2 = ya.x * ya.x + ya.y * ya.y + ya.z * ya.z + ya.w * ya.w +
             yb.x * yb.x + yb.y * yb.y + yb.z * yb.z + yb.w * yb.w;

#pragma unroll
  for (int m = 1; m < 64; m <<= 1) {
    d1 += __shfl_xor(d1, m, 64);
    d2 += __shfl_xor(d2, m, 64);
    qq += __shfl_xor(qq, m, 64);
    i1 += __shfl_xor(i1, m, 64);
    i2 += __shfl_xor(i2, m, 64);
  }

  if (lane == 0) {
    bool use2 = (d2 > d1) || (d2 == d1 && c2i < c1i);
    float d  = use2 ? d2 : d1;
    float nn = use2 ? i2 : i1;
    float nq = fmaxf(sqrtf(qq), 1e-12f);
    float np = fmaxf(sqrtf(nn), 1e-12f);
    out[qrow] = -(d / (nq * np));
  }
}

// ---------------------------------------------------------------------------
extern "C" void kernel_launch(void* const* d_in, const int* in_sizes, int n_in,
                              void* d_out, int out_size, void* d_ws,
                              size_t ws_size, hipStream_t stream) {
  const float* q  = (const float*)d_in[0];
  const float* it = (const float*)d_in[1];
  char* ws = (char*)d_ws;
  float* out = (float*)d_out;

  convert_kernel<<<TQ * CD / 4 / 256, 256, 0, stream>>>(q, it, ws);
  dim3 grid(TQ / BM, NSPLIT);
  score_kernel<<<grid, 256, 0, stream>>>(ws);
  rescue_kernel<<<TQ / 4, 256, 0, stream>>>(q, it, ws, out);
}